// Round 8
// baseline (375.929 us; speedup 1.0000x reference)
//
#include <hip/hip_runtime.h>
#include <hip/hip_fp16.h>
#include <hip/hip_cooperative_groups.h>

namespace cg = cooperative_groups;

#define N_NODES 20000
#define N_EDGES 40000
#define N_GRAPHS 500
#define D_IN 32
#define D_E 16
#define H1 100
#define H2 20
#define F1 50

#define EB1 64    // edges per tile, MFMA phases
#define YNB 12    // nodes per tile, node1
#define ET3 12    // nodes per tile, node2_pool
#define NT_E 625  // edge tiles (625*64 = 40000)
#define NT_N 1667 // node tiles (ceil(20000/12))

using h2f = __attribute__((ext_vector_type(2))) _Float16;
using h8f = __attribute__((ext_vector_type(8))) _Float16;
using f4  = __attribute__((ext_vector_type(4))) float;

union SMemU {
  struct { uint4 P[4 * 64]; uint4 B[2][7 * 64]; int sdst[EB1]; } e1;   // 18.5 KB
  struct { uint4 P[4][4][64]; uint4 B[2][512]; int sdst[EB1]; } e2;    // 32.3 KB
  struct { float sroot1[D_IN * H1]; float sxl[YNB * D_IN]; } n1;       // 14.3 KB
  struct { float sroot[H1 * H2]; float sv[ET3][H2]; int sg[ET3]; } n2; //  9.4 KB
};

// ===========================================================================
// Mega-kernel: whole GNN forward in one cooperative launch, 6 phases.
// ===========================================================================
__global__ __launch_bounds__(256, 2) void mega_kernel(
    const float* __restrict__ x, const float* __restrict__ ea,
    const int* __restrict__ eidx, const int* __restrict__ batch,
    const float* __restrict__ nn1W, const float* __restrict__ nn1b,
    const float* __restrict__ root1, const float* __restrict__ bias1,
    const float* __restrict__ nn2W, const float* __restrict__ nn2b,
    const float* __restrict__ root2, const float* __restrict__ bias2,
    const float* __restrict__ lin1W, const float* __restrict__ lin1b,
    const float* __restrict__ lin2W, const float* __restrict__ lin2b,
    float* __restrict__ out, float* __restrict__ agg1, float* __restrict__ agg2,
    float* __restrict__ g, float* __restrict__ h1,
    unsigned short* __restrict__ Wfrag1, unsigned short* __restrict__ Wfrag2)
{
  cg::grid_group grid = cg::this_grid();
  __shared__ SMemU sm;

  const int t       = threadIdx.x;
  const int lane    = t & 63;
  const int w       = t >> 6;
  const int gstride = gridDim.x * 256;

  // ---------------- Phase 0: prep Wfrag1/Wfrag2 + zero agg1|agg2|g ---------
  {
    for (int tid = blockIdx.x * 256 + t; tid < 130560; tid += gstride) {
      if (tid < 60928) {
        const int c  = tid / 3584;
        const int r  = tid % 3584;
        const int to = r / 512;
        const int l  = (r % 512) >> 3;
        const int j  = r & 7;
        const int i  = (l >> 4) * 8 + j;
        const int o  = to * 16 + (l & 15);
        float v = 0.f;
        if (o < H1) v = (c < 16) ? nn1W[c * (D_IN * H1) + i * H1 + o] : nn1b[i * H1 + o];
        _Float16 hv = (_Float16)v;
        Wfrag1[tid] = __builtin_bit_cast(unsigned short, hv);
      } else {
        const int t2 = tid - 60928;
        const int c  = t2 >> 12;
        const int q  = (t2 >> 10) & 3;
        const int to = (t2 >> 9) & 1;
        const int l  = (t2 >> 3) & 63;
        const int j  = t2 & 7;
        const int i  = q * 32 + (l >> 4) * 8 + j;
        const int o  = to * 16 + (l & 15);
        float v = 0.f;
        if (i < H1 && o < H2)
          v = (c < 16) ? nn2W[c * (H1 * H2) + i * H2 + o] : nn2b[i * H2 + o];
        _Float16 hv = (_Float16)v;
        Wfrag2[t2] = __builtin_bit_cast(unsigned short, hv);
      }
    }
    float4* zp = (float4*)agg1;   // agg1|agg2|g contiguous = 602,500 float4
    for (int i = blockIdx.x * 256 + t; i < 602500; i += gstride)
      zp[i] = make_float4(0.f, 0.f, 0.f, 0.f);
  }
  grid.sync();

  // ---------------- Phase 1: edge1 (fp16 MFMA) -----------------------------
  {
    const uint4* __restrict__ Bf = (const uint4*)Wfrag1;
    for (int tile = blockIdx.x; tile < NT_E; tile += gridDim.x) {
      __syncthreads();   // protect prior iteration's LDS readers
      const int e0    = tile * EB1;
      const int e_loc = t >> 2;
      const int jg    = t & 3;
      const int src   = eidx[e0 + e_loc];

      h2f xh[4];
      {
        const float4* xp = (const float4*)&x[(size_t)src * D_IN + jg * 8];
        float4 v0 = xp[0], v1 = xp[1];
        float xf[8] = {v0.x, v0.y, v0.z, v0.w, v1.x, v1.y, v1.z, v1.w};
        #pragma unroll
        for (int j = 0; j < 4; ++j) {
          h2f p; p[0] = (_Float16)xf[2*j]; p[1] = (_Float16)xf[2*j+1]; xh[j] = p;
        }
      }
      _Float16 eh[17];
      {
        const float4* ep = (const float4*)&ea[(size_t)(e0 + e_loc) * D_E];
        float4 v0 = ep[0], v1 = ep[1], v2 = ep[2], v3 = ep[3];
        float ef[16] = {v0.x,v0.y,v0.z,v0.w, v1.x,v1.y,v1.z,v1.w,
                        v2.x,v2.y,v2.z,v2.w, v3.x,v3.y,v3.z,v3.w};
        #pragma unroll
        for (int k = 0; k < 16; ++k) eh[k] = (_Float16)ef[k];
        eh[16] = (_Float16)1.0f;
      }
      if (t < EB1) sm.e1.sdst[t] = eidx[N_EDGES + e0 + t];

      {
        uint4 s0 = Bf[t];
        uint4 s1;
        if (t < 192) s1 = Bf[256 + t];
        sm.e1.B[0][t] = s0;
        if (t < 192) sm.e1.B[0][256 + t] = s1;
      }
      __syncthreads();

      f4 acc[7];
      #pragma unroll
      for (int to = 0; to < 7; ++to) acc[to] = f4{0.f, 0.f, 0.f, 0.f};

      const int pslot = w * 64 + (e_loc & 15) + 16 * jg;

      #pragma unroll
      for (int c = 0; c < 17; ++c) {
        uint4 s0, s1;
        if (c < 16) {
          const uint4* bn = Bf + (c + 1) * 448;
          s0 = bn[t];
          if (t < 192) s1 = bn[256 + t];
        }

        h2f es; es[0] = eh[c]; es[1] = eh[c];
        unsigned int pk[4];
        #pragma unroll
        for (int j = 0; j < 4; ++j) {
          h2f pr = xh[j] * es;
          pk[j] = __builtin_bit_cast(unsigned int, pr);
        }
        sm.e1.P[pslot] = make_uint4(pk[0], pk[1], pk[2], pk[3]);

        uint4 a = sm.e1.P[w * 64 + lane];
        h8f A = __builtin_bit_cast(h8f, a);

        const uint4* bb = &sm.e1.B[c & 1][0];
        #pragma unroll
        for (int to = 0; to < 7; ++to) {
          h8f B = __builtin_bit_cast(h8f, bb[to * 64 + lane]);
          acc[to] = __builtin_amdgcn_mfma_f32_16x16x32_f16(A, B, acc[to], 0, 0, 0);
        }

        if (c < 16) {
          sm.e1.B[(c + 1) & 1][t] = s0;
          if (t < 192) sm.e1.B[(c + 1) & 1][256 + t] = s1;
        }
        __syncthreads();
      }

      const int col = lane & 15, rowg = lane >> 4;
      #pragma unroll
      for (int r = 0; r < 4; ++r) {
        const int el = w * 16 + rowg * 4 + r;
        const int d = sm.e1.sdst[el];
        float* ap = agg1 + (size_t)d * H1;
        #pragma unroll
        for (int to = 0; to < 7; ++to) {
          const int o = to * 16 + col;
          if (o < H1) unsafeAtomicAdd(&ap[o], acc[to][r]);
        }
      }
    }
  }
  grid.sync();

  // ---------------- Phase 2: node1 h1 = relu(agg1 + x@root1 + bias1) -------
  {
    for (int idx = t; idx < 800; idx += 256)
      *(float4*)&sm.n1.sroot1[idx * 4] = *(const float4*)&root1[idx * 4];
    for (int tile = blockIdx.x; tile < NT_N; tile += gridDim.x) {
      __syncthreads();
      const int n0 = tile * YNB;
      if (t < 96) {
        const int fo = t * 4;
        const int nn = fo >> 5;
        float4 v = make_float4(0.f, 0.f, 0.f, 0.f);
        if (n0 + nn < N_NODES) v = *(const float4*)&x[(size_t)n0 * D_IN + fo];
        *(float4*)&sm.n1.sxl[fo] = v;
      }
      __syncthreads();
      for (int idx = t; idx < YNB * H1; idx += 256) {
        const int nn = idx / H1, i = idx - nn * H1;
        const int n = n0 + nn;
        if (n < N_NODES) {
          float v = agg1[(size_t)n0 * H1 + idx] + bias1[i];
          #pragma unroll 8
          for (int d = 0; d < D_IN; ++d)
            v = fmaf(sm.n1.sxl[nn * D_IN + d], sm.n1.sroot1[d * H1 + i], v);
          h1[(size_t)n0 * H1 + idx] = fmaxf(v, 0.f);
        }
      }
    }
  }
  grid.sync();

  // ---------------- Phase 3: edge2m (fp16 MFMA) ----------------------------
  {
    const uint4* __restrict__ Bf = (const uint4*)Wfrag2;
    for (int tile = blockIdx.x; tile < NT_E; tile += gridDim.x) {
      __syncthreads();
      const int e0    = tile * EB1;
      const int e_loc = t >> 2;
      const int jg    = t & 3;
      const int m     = e_loc & 15;
      const int src   = eidx[e0 + e_loc];

      h2f xh[16];
      {
        float xf[32];
        const float* hp = &h1[(size_t)src * H1 + jg * 32];
        if (jg < 3) {
          #pragma unroll
          for (int q4 = 0; q4 < 8; ++q4) {
            float4 v = *(const float4*)&hp[q4 * 4];
            xf[q4*4+0] = v.x; xf[q4*4+1] = v.y; xf[q4*4+2] = v.z; xf[q4*4+3] = v.w;
          }
        } else {
          float4 v = *(const float4*)hp;
          xf[0] = v.x; xf[1] = v.y; xf[2] = v.z; xf[3] = v.w;
          #pragma unroll
          for (int ii = 4; ii < 32; ++ii) xf[ii] = 0.f;
        }
        #pragma unroll
        for (int j2 = 0; j2 < 16; ++j2) {
          h2f p; p[0] = (_Float16)xf[2*j2]; p[1] = (_Float16)xf[2*j2+1]; xh[j2] = p;
        }
      }
      _Float16 eh[17];
      {
        const float4* ep = (const float4*)&ea[(size_t)(e0 + e_loc) * D_E];
        float4 v0 = ep[0], v1 = ep[1], v2 = ep[2], v3 = ep[3];
        float ef[16] = {v0.x,v0.y,v0.z,v0.w, v1.x,v1.y,v1.z,v1.w,
                        v2.x,v2.y,v2.z,v2.w, v3.x,v3.y,v3.z,v3.w};
        #pragma unroll
        for (int k = 0; k < 16; ++k) eh[k] = (_Float16)ef[k];
        eh[16] = (_Float16)1.0f;
      }
      if (t < EB1) sm.e2.sdst[t] = eidx[N_EDGES + e0 + t];

      {
        uint4 s0 = Bf[t];
        uint4 s1 = Bf[256 + t];
        sm.e2.B[0][t] = s0;
        sm.e2.B[0][256 + t] = s1;
      }
      {
        h2f es; es[0] = eh[0]; es[1] = eh[0];
        unsigned int pk[16];
        #pragma unroll
        for (int j2 = 0; j2 < 16; ++j2) {
          h2f pr = xh[j2] * es;
          pk[j2] = __builtin_bit_cast(unsigned int, pr);
        }
        #pragma unroll
        for (int oc = 0; oc < 4; ++oc)
          sm.e2.P[w][jg][16 * oc + m] = make_uint4(pk[4*oc], pk[4*oc+1], pk[4*oc+2], pk[4*oc+3]);
      }
      __syncthreads();

      f4 acc0 = f4{0.f, 0.f, 0.f, 0.f};
      f4 acc1 = f4{0.f, 0.f, 0.f, 0.f};

      #pragma unroll
      for (int c = 0; c < 17; ++c) {
        const int buf = c & 1;
        uint4 s0, s1;
        if (c < 16) {
          const uint4* bn = Bf + (c + 1) * 512;
          s0 = bn[t];
          s1 = bn[256 + t];
        }

        #pragma unroll
        for (int q = 0; q < 4; ++q) {
          uint4 a  = sm.e2.P[w][q][lane];
          uint4 b0 = sm.e2.B[buf][q * 128 + lane];
          uint4 b1 = sm.e2.B[buf][q * 128 + 64 + lane];
          h8f A  = __builtin_bit_cast(h8f, a);
          h8f B0 = __builtin_bit_cast(h8f, b0);
          h8f B1 = __builtin_bit_cast(h8f, b1);
          acc0 = __builtin_amdgcn_mfma_f32_16x16x32_f16(A, B0, acc0, 0, 0, 0);
          acc1 = __builtin_amdgcn_mfma_f32_16x16x32_f16(A, B1, acc1, 0, 0, 0);
        }

        if (c < 16) {
          h2f es; es[0] = eh[c + 1]; es[1] = eh[c + 1];
          unsigned int pk[16];
          #pragma unroll
          for (int j2 = 0; j2 < 16; ++j2) {
            h2f pr = xh[j2] * es;
            pk[j2] = __builtin_bit_cast(unsigned int, pr);
          }
          #pragma unroll
          for (int oc = 0; oc < 4; ++oc)
            sm.e2.P[w][jg][16 * oc + m] = make_uint4(pk[4*oc], pk[4*oc+1], pk[4*oc+2], pk[4*oc+3]);
          sm.e2.B[buf ^ 1][t] = s0;
          sm.e2.B[buf ^ 1][256 + t] = s1;
          __syncthreads();
        }
      }

      const int col = lane & 15, rowg = lane >> 4;
      #pragma unroll
      for (int r = 0; r < 4; ++r) {
        const int el = w * 16 + rowg * 4 + r;
        const int d  = sm.e2.sdst[el];
        float* ap = agg2 + (size_t)d * H2;
        unsafeAtomicAdd(&ap[col], acc0[r]);
        if (col < 4) unsafeAtomicAdd(&ap[16 + col], acc1[r]);
      }
    }
  }
  grid.sync();

  // ---------------- Phase 4: node2 + sum-pool ------------------------------
  {
    for (int idx = t; idx < 500; idx += 256)
      *(float4*)&sm.n2.sroot[idx * 4] = *(const float4*)&root2[idx * 4];
    for (int tile = blockIdx.x; tile < NT_N; tile += gridDim.x) {
      __syncthreads();
      const int n0 = tile * ET3;
      if (t < ET3) {
        const int n = n0 + t;
        sm.n2.sg[t] = (n < N_NODES) ? batch[n] : -1;
      }
      const int nl = t / H2, o = t % H2;
      const int n = n0 + nl;
      if (nl < ET3) {
        float v = 0.f;
        if (n < N_NODES) {
          v = agg2[(size_t)n * H2 + o] + bias2[o];
          const float* hr = &h1[(size_t)n * H1];
          #pragma unroll 5
          for (int i = 0; i < H1; i += 4) {
            const float4 hv = *(const float4*)&hr[i];
            v = fmaf(hv.x, sm.n2.sroot[(i    ) * H2 + o], v);
            v = fmaf(hv.y, sm.n2.sroot[(i + 1) * H2 + o], v);
            v = fmaf(hv.z, sm.n2.sroot[(i + 2) * H2 + o], v);
            v = fmaf(hv.w, sm.n2.sroot[(i + 3) * H2 + o], v);
          }
          v = fmaxf(v, 0.f);
        }
        sm.n2.sv[nl][o] = v;
      }
      __syncthreads();
      if (t < H2) {
        float run = 0.f;
        int cur = sm.n2.sg[0];
        #pragma unroll
        for (int r = 0; r < ET3; ++r) {
          const int gid = sm.n2.sg[r];
          if (gid != cur) {
            if (cur >= 0) unsafeAtomicAdd(&g[cur * H2 + t], run);
            run = 0.f; cur = gid;
          }
          run += sm.n2.sv[r][t];
        }
        if (cur >= 0) unsafeAtomicAdd(&g[cur * H2 + t], run);
      }
    }
  }
  grid.sync();

  // ---------------- Phase 5: final MLP (4 graphs/block, wave each) ---------
  {
    for (int gb = blockIdx.x; gb < 125; gb += gridDim.x) {
      const int gr = gb * 4 + w;
      float v = 0.f;
      if (lane < F1) {
        float s = lin1b[lane];
        #pragma unroll
        for (int o = 0; o < H2; ++o) s = fmaf(g[gr * H2 + o], lin1W[o * F1 + lane], s);
        v = fmaxf(s, 0.f) * lin2W[lane];
      }
      #pragma unroll
      for (int off = 32; off > 0; off >>= 1) v += __shfl_down(v, off, 64);
      if (lane == 0) out[gr] = v + lin2b[0];
    }
  }
}

// ===========================================================================
// Fallback: round-7 six-kernel pipeline (used only if cooperative launch
// is unavailable / fails under graph capture).
// ===========================================================================
__global__ __launch_bounds__(256) void prep_kernel(
    const float* __restrict__ nn1W, const float* __restrict__ nn1b,
    const float* __restrict__ nn2W, const float* __restrict__ nn2b,
    unsigned short* __restrict__ Wfrag1, unsigned short* __restrict__ Wfrag2,
    float* __restrict__ zbase)
{
  const int tid = blockIdx.x * 256 + threadIdx.x;
  if (tid < 544 * 112) {
    const int c  = tid / 3584;
    const int r  = tid % 3584;
    const int to = r / 512;
    const int l  = (r % 512) >> 3;
    const int j  = r & 7;
    const int i  = (l >> 4) * 8 + j;
    const int o  = to * 16 + (l & 15);
    float v = 0.f;
    if (o < H1) v = (c < 16) ? nn1W[c * (D_IN * H1) + i * H1 + o] : nn1b[i * H1 + o];
    _Float16 hv = (_Float16)v;
    Wfrag1[tid] = __builtin_bit_cast(unsigned short, hv);
  } else if (tid < 544 * 112 + 17 * 4096) {
    const int t2 = tid - 544 * 112;
    const int c  = t2 >> 12;
    const int q  = (t2 >> 10) & 3;
    const int to = (t2 >> 9) & 1;
    const int l  = (t2 >> 3) & 63;
    const int j  = t2 & 7;
    const int i  = q * 32 + (l >> 4) * 8 + j;
    const int o  = to * 16 + (l & 15);
    float v = 0.f;
    if (i < H1 && o < H2)
      v = (c < 16) ? nn2W[c * (H1 * H2) + i * H2 + o] : nn2b[i * H2 + o];
    _Float16 hv = (_Float16)v;
    Wfrag2[t2] = __builtin_bit_cast(unsigned short, hv);
  }
  float4* zp = (float4*)zbase;
  for (int i = tid; i < 602500; i += 512 * 256)
    zp[i] = make_float4(0.f, 0.f, 0.f, 0.f);
}

__global__ __launch_bounds__(256, 3) void edge1_kernel(
    const float* __restrict__ x, const float* __restrict__ ea,
    const int* __restrict__ eidx, const unsigned short* __restrict__ Wfrag,
    float* __restrict__ agg1)
{
  __shared__ uint4 Plds[4 * 64];
  __shared__ uint4 Blds[2][7 * 64];
  __shared__ int   sdst[EB1];

  const int t    = threadIdx.x;
  const int lane = t & 63;
  const int w    = t >> 6;
  const int e0   = blockIdx.x * EB1;

  const int e_loc = t >> 2;
  const int jg    = t & 3;
  const int src   = eidx[e0 + e_loc];

  h2f xh[4];
  {
    const float4* xp = (const float4*)&x[(size_t)src * D_IN + jg * 8];
    float4 v0 = xp[0], v1 = xp[1];
    float xf[8] = {v0.x, v0.y, v0.z, v0.w, v1.x, v1.y, v1.z, v1.w};
    #pragma unroll
    for (int j = 0; j < 4; ++j) {
      h2f p; p[0] = (_Float16)xf[2*j]; p[1] = (_Float16)xf[2*j+1]; xh[j] = p;
    }
  }
  _Float16 eh[17];
  {
    const float4* ep = (const float4*)&ea[(size_t)(e0 + e_loc) * D_E];
    float4 v0 = ep[0], v1 = ep[1], v2 = ep[2], v3 = ep[3];
    float ef[16] = {v0.x,v0.y,v0.z,v0.w, v1.x,v1.y,v1.z,v1.w,
                    v2.x,v2.y,v2.z,v2.w, v3.x,v3.y,v3.z,v3.w};
    #pragma unroll
    for (int k = 0; k < 16; ++k) eh[k] = (_Float16)ef[k];
    eh[16] = (_Float16)1.0f;
  }
  if (t < EB1) sdst[t] = eidx[N_EDGES + e0 + t];

  const uint4* __restrict__ Bf = (const uint4*)Wfrag;
  {
    uint4 s0 = Bf[t];
    uint4 s1;
    if (t < 192) s1 = Bf[256 + t];
    Blds[0][t] = s0;
    if (t < 192) Blds[0][256 + t] = s1;
  }
  __syncthreads();

  f4 acc[7];
  #pragma unroll
  for (int to = 0; to < 7; ++to) acc[to] = f4{0.f, 0.f, 0.f, 0.f};

  const int pslot = w * 64 + (e_loc & 15) + 16 * jg;

  #pragma unroll
  for (int c = 0; c < 17; ++c) {
    uint4 s0, s1;
    if (c < 16) {
      const uint4* bn = Bf + (c + 1) * 448;
      s0 = bn[t];
      if (t < 192) s1 = bn[256 + t];
    }
    h2f es; es[0] = eh[c]; es[1] = eh[c];
    unsigned int pk[4];
    #pragma unroll
    for (int j = 0; j < 4; ++j) {
      h2f pr = xh[j] * es;
      pk[j] = __builtin_bit_cast(unsigned int, pr);
    }
    Plds[pslot] = make_uint4(pk[0], pk[1], pk[2], pk[3]);

    uint4 a = Plds[w * 64 + lane];
    h8f A = __builtin_bit_cast(h8f, a);

    const uint4* bb = &Blds[c & 1][0];
    #pragma unroll
    for (int to = 0; to < 7; ++to) {
      h8f B = __builtin_bit_cast(h8f, bb[to * 64 + lane]);
      acc[to] = __builtin_amdgcn_mfma_f32_16x16x32_f16(A, B, acc[to], 0, 0, 0);
    }
    if (c < 16) {
      Blds[(c + 1) & 1][t] = s0;
      if (t < 192) Blds[(c + 1) & 1][256 + t] = s1;
    }
    __syncthreads();
  }

  const int col = lane & 15, rowg = lane >> 4;
  #pragma unroll
  for (int r = 0; r < 4; ++r) {
    const int el = w * 16 + rowg * 4 + r;
    const int d = sdst[el];
    float* ap = agg1 + (size_t)d * H1;
    #pragma unroll
    for (int to = 0; to < 7; ++to) {
      const int o = to * 16 + col;
      if (o < H1) unsafeAtomicAdd(&ap[o], acc[to][r]);
    }
  }
}

__global__ __launch_bounds__(256) void node1_kernel(
    const float* __restrict__ x, const float* __restrict__ agg1,
    const float* __restrict__ root1, const float* __restrict__ bias1,
    float* __restrict__ h1)
{
  __shared__ float sroot1[D_IN * H1];
  __shared__ float sxl[YNB * D_IN];
  const int t  = threadIdx.x;
  const int n0 = blockIdx.x * YNB;

  for (int idx = t; idx < 800; idx += 256)
    *(float4*)&sroot1[idx * 4] = *(const float4*)&root1[idx * 4];
  if (t < 96) {
    const int fo = t * 4;
    const int nn = fo >> 5;
    float4 v = make_float4(0.f, 0.f, 0.f, 0.f);
    if (n0 + nn < N_NODES) v = *(const float4*)&x[(size_t)n0 * D_IN + fo];
    *(float4*)&sxl[fo] = v;
  }
  __syncthreads();

  for (int idx = t; idx < YNB * H1; idx += 256) {
    const int nn = idx / H1, i = idx - nn * H1;
    const int n = n0 + nn;
    if (n < N_NODES) {
      float v = agg1[(size_t)n0 * H1 + idx] + bias1[i];
      #pragma unroll 8
      for (int d = 0; d < D_IN; ++d)
        v = fmaf(sxl[nn * D_IN + d], sroot1[d * H1 + i], v);
      h1[(size_t)n0 * H1 + idx] = fmaxf(v, 0.f);
    }
  }
}

__global__ __launch_bounds__(256, 3) void edge2m_kernel(
    const float* __restrict__ h1, const float* __restrict__ ea,
    const int* __restrict__ eidx, const unsigned short* __restrict__ Wfrag2,
    float* __restrict__ agg2)
{
  __shared__ uint4 Plds[4][4][64];
  __shared__ uint4 Blds[2][512];
  __shared__ int   sdst[EB1];

  const int t    = threadIdx.x;
  const int lane = t & 63;
  const int w    = t >> 6;
  const int e0   = blockIdx.x * EB1;

  const int e_loc = t >> 2;
  const int jg    = t & 3;
  const int m     = e_loc & 15;
  const int src   = eidx[e0 + e_loc];

  h2f xh[16];
  {
    float xf[32];
    const float* hp = &h1[(size_t)src * H1 + jg * 32];
    if (jg < 3) {
      #pragma unroll
      for (int q4 = 0; q4 < 8; ++q4) {
        float4 v = *(const float4*)&hp[q4 * 4];
        xf[q4*4+0] = v.x; xf[q4*4+1] = v.y; xf[q4*4+2] = v.z; xf[q4*4+3] = v.w;
      }
    } else {
      float4 v = *(const float4*)hp;
      xf[0] = v.x; xf[1] = v.y; xf[2] = v.z; xf[3] = v.w;
      #pragma unroll
      for (int ii = 4; ii < 32; ++ii) xf[ii] = 0.f;
    }
    #pragma unroll
    for (int j2 = 0; j2 < 16; ++j2) {
      h2f p; p[0] = (_Float16)xf[2*j2]; p[1] = (_Float16)xf[2*j2+1]; xh[j2] = p;
    }
  }
  _Float16 eh[17];
  {
    const float4* ep = (const float4*)&ea[(size_t)(e0 + e_loc) * D_E];
    float4 v0 = ep[0], v1 = ep[1], v2 = ep[2], v3 = ep[3];
    float ef[16] = {v0.x,v0.y,v0.z,v0.w, v1.x,v1.y,v1.z,v1.w,
                    v2.x,v2.y,v2.z,v2.w, v3.x,v3.y,v3.z,v3.w};
    #pragma unroll
    for (int k = 0; k < 16; ++k) eh[k] = (_Float16)ef[k];
    eh[16] = (_Float16)1.0f;
  }
  if (t < EB1) sdst[t] = eidx[N_EDGES + e0 + t];

  const uint4* __restrict__ Bf = (const uint4*)Wfrag2;
  {
    uint4 s0 = Bf[t];
    uint4 s1 = Bf[256 + t];
    Blds[0][t] = s0;
    Blds[0][256 + t] = s1;
  }
  {
    h2f es; es[0] = eh[0]; es[1] = eh[0];
    unsigned int pk[16];
    #pragma unroll
    for (int j2 = 0; j2 < 16; ++j2) {
      h2f pr = xh[j2] * es;
      pk[j2] = __builtin_bit_cast(unsigned int, pr);
    }
    #pragma unroll
    for (int oc = 0; oc < 4; ++oc)
      Plds[w][jg][16 * oc + m] = make_uint4(pk[4*oc], pk[4*oc+1], pk[4*oc+2], pk[4*oc+3]);
  }
  __syncthreads();

  f4 acc0 = f4{0.f, 0.f, 0.f, 0.f};
  f4 acc1 = f4{0.f, 0.f, 0.f, 0.f};

  #pragma unroll
  for (int c = 0; c < 17; ++c) {
    const int buf = c & 1;
    uint4 s0, s1;
    if (c < 16) {
      const uint4* bn = Bf + (c + 1) * 512;
      s0 = bn[t];
      s1 = bn[256 + t];
    }
    #pragma unroll
    for (int q = 0; q < 4; ++q) {
      uint4 a  = Plds[w][q][lane];
      uint4 b0 = Blds[buf][q * 128 + lane];
      uint4 b1 = Blds[buf][q * 128 + 64 + lane];
      h8f A  = __builtin_bit_cast(h8f, a);
      h8f B0 = __builtin_bit_cast(h8f, b0);
      h8f B1 = __builtin_bit_cast(h8f, b1);
      acc0 = __builtin_amdgcn_mfma_f32_16x16x32_f16(A, B0, acc0, 0, 0, 0);
      acc1 = __builtin_amdgcn_mfma_f32_16x16x32_f16(A, B1, acc1, 0, 0, 0);
    }
    if (c < 16) {
      h2f es; es[0] = eh[c + 1]; es[1] = eh[c + 1];
      unsigned int pk[16];
      #pragma unroll
      for (int j2 = 0; j2 < 16; ++j2) {
        h2f pr = xh[j2] * es;
        pk[j2] = __builtin_bit_cast(unsigned int, pr);
      }
      #pragma unroll
      for (int oc = 0; oc < 4; ++oc)
        Plds[w][jg][16 * oc + m] = make_uint4(pk[4*oc], pk[4*oc+1], pk[4*oc+2], pk[4*oc+3]);
      Blds[buf ^ 1][t] = s0;
      Blds[buf ^ 1][256 + t] = s1;
      __syncthreads();
    }
  }

  const int col = lane & 15, rowg = lane >> 4;
  #pragma unroll
  for (int r = 0; r < 4; ++r) {
    const int el = w * 16 + rowg * 4 + r;
    const int d  = sdst[el];
    float* ap = agg2 + (size_t)d * H2;
    unsafeAtomicAdd(&ap[col], acc0[r]);
    if (col < 4) unsafeAtomicAdd(&ap[16 + col], acc1[r]);
  }
}

__global__ __launch_bounds__(256) void node2_pool_kernel(
    const float* __restrict__ h1, const float* __restrict__ agg2,
    const float* __restrict__ root2, const float* __restrict__ bias2,
    const int* __restrict__ batch, float* __restrict__ g)
{
  __shared__ float sroot[H1 * H2];
  __shared__ float sv[ET3][H2];
  __shared__ int   sg[ET3];
  const int t  = threadIdx.x;
  const int n0 = blockIdx.x * ET3;

  for (int idx = t; idx < (H1 * H2) / 4; idx += 256)
    *(float4*)&sroot[idx * 4] = *(const float4*)&root2[idx * 4];
  if (t < ET3) {
    const int n = n0 + t;
    sg[t] = (n < N_NODES) ? batch[n] : -1;
  }
  __syncthreads();

  const int nl = t / H2, o = t % H2;
  const int n = n0 + nl;
  if (nl < ET3) {
    float v = 0.f;
    if (n < N_NODES) {
      v = agg2[(size_t)n * H2 + o] + bias2[o];
      const float* hr = &h1[(size_t)n * H1];
      #pragma unroll 5
      for (int i = 0; i < H1; i += 4) {
        const float4 hv = *(const float4*)&hr[i];
        v = fmaf(hv.x, sroot[(i    ) * H2 + o], v);
        v = fmaf(hv.y, sroot[(i + 1) * H2 + o], v);
        v = fmaf(hv.z, sroot[(i + 2) * H2 + o], v);
        v = fmaf(hv.w, sroot[(i + 3) * H2 + o], v);
      }
      v = fmaxf(v, 0.f);
    }
    sv[nl][o] = v;
  }
  __syncthreads();

  if (t < H2) {
    float run = 0.f;
    int cur = sg[0];
    #pragma unroll
    for (int r = 0; r < ET3; ++r) {
      const int gid = sg[r];
      if (gid != cur) {
        if (cur >= 0) unsafeAtomicAdd(&g[cur * H2 + t], run);
        run = 0.f; cur = gid;
      }
      run += sv[r][t];
    }
    if (cur >= 0) unsafeAtomicAdd(&g[cur * H2 + t], run);
  }
}

__global__ __launch_bounds__(64) void final_kernel(
    const float* __restrict__ g, const float* __restrict__ lin1W,
    const float* __restrict__ lin1b, const float* __restrict__ lin2W,
    const float* __restrict__ lin2b, float* __restrict__ out)
{
  const int gr = blockIdx.x;
  const int tt = threadIdx.x;
  float v = 0.f;
  if (tt < F1) {
    float s = lin1b[tt];
    #pragma unroll
    for (int o = 0; o < H2; ++o) s = fmaf(g[gr * H2 + o], lin1W[o * F1 + tt], s);
    v = fmaxf(s, 0.f) * lin2W[tt];
  }
  #pragma unroll
  for (int off = 32; off > 0; off >>= 1) v += __shfl_down(v, off, 64);
  if (tt == 0) out[gr] = v + lin2b[0];
}

// ===========================================================================
extern "C" void kernel_launch(void* const* d_in, const int* in_sizes, int n_in,
                              void* d_out, int out_size, void* d_ws, size_t ws_size,
                              hipStream_t stream) {
  const float* x     = (const float*)d_in[0];
  const float* ea    = (const float*)d_in[1];
  const int*   eidx  = (const int*)d_in[2];
  const int*   batch = (const int*)d_in[3];
  const float* nn1W  = (const float*)d_in[4];
  const float* nn1b  = (const float*)d_in[5];
  const float* root1 = (const float*)d_in[6];
  const float* bias1 = (const float*)d_in[7];
  const float* nn2W  = (const float*)d_in[8];
  const float* nn2b  = (const float*)d_in[9];
  const float* root2 = (const float*)d_in[10];
  const float* bias2 = (const float*)d_in[11];
  const float* lin1W = (const float*)d_in[12];
  const float* lin1b = (const float*)d_in[13];
  const float* lin2W = (const float*)d_in[14];
  const float* lin2b = (const float*)d_in[15];
  float* out = (float*)d_out;

  float* ws   = (float*)d_ws;
  float* agg1 = ws;                          // 2,000,000 floats
  float* agg2 = agg1 + N_NODES * H1;         //   400,000
  float* g    = agg2 + N_NODES * H2;         //    10,000
  float* h1   = g    + N_GRAPHS * H2;        // 2,000,000
  unsigned short* Wfrag1 = (unsigned short*)(h1 + (size_t)N_NODES * H1);  // 60,928 u16
  unsigned short* Wfrag2 = Wfrag1 + 61440;                                // 69,632 u16

  int maxb = 0;
  hipError_t qe = hipOccupancyMaxActiveBlocksPerMultiprocessor(
      &maxb, reinterpret_cast<const void*>(&mega_kernel), 256, 0);
  int nblk = 256;
  if (qe == hipSuccess && maxb >= 1) {
    int cap = maxb * 256;
    nblk = cap < 512 ? cap : 512;
  }

  void* kargs[] = {
      (void*)&x, (void*)&ea, (void*)&eidx, (void*)&batch,
      (void*)&nn1W, (void*)&nn1b, (void*)&root1, (void*)&bias1,
      (void*)&nn2W, (void*)&nn2b, (void*)&root2, (void*)&bias2,
      (void*)&lin1W, (void*)&lin1b, (void*)&lin2W, (void*)&lin2b,
      (void*)&out, (void*)&agg1, (void*)&agg2, (void*)&g, (void*)&h1,
      (void*)&Wfrag1, (void*)&Wfrag2};

  hipError_t le = hipLaunchCooperativeKernel(
      reinterpret_cast<const void*>(&mega_kernel), dim3(nblk), dim3(256),
      kargs, 0, stream);

  if (le != hipSuccess) {
    // Fallback: proven 6-kernel pipeline (round 7)
    prep_kernel<<<512, 256, 0, stream>>>(nn1W, nn1b, nn2W, nn2b, Wfrag1, Wfrag2, agg1);
    edge1_kernel<<<N_EDGES / EB1, 256, 0, stream>>>(x, ea, eidx, Wfrag1, agg1);
    node1_kernel<<<(N_NODES + YNB - 1) / YNB, 256, 0, stream>>>(
        x, agg1, root1, bias1, h1);
    edge2m_kernel<<<N_EDGES / EB1, 256, 0, stream>>>(h1, ea, eidx, Wfrag2, agg2);
    node2_pool_kernel<<<(N_NODES + ET3 - 1) / ET3, 256, 0, stream>>>(
        h1, agg2, root2, bias2, batch, g);
    final_kernel<<<N_GRAPHS, 64, 0, stream>>>(g, lin1W, lin1b, lin2W, lin2b, out);
  }
}

// Round 10
// 174.494 us; speedup vs baseline: 2.1544x; 2.1544x over previous
//
#include <hip/hip_runtime.h>
#include <hip/hip_fp16.h>

#define N_NODES 20000
#define N_EDGES 40000
#define N_GRAPHS 500
#define D_IN 32
#define D_E 16
#define H1 100
#define H2 20
#define F1 50

#define EB1 64    // edges per block, MFMA kernels
#define YNB 12    // nodes per tile, pre1 phase in prep
#define ET3 12    // nodes per block, node2_pool

using h2f = __attribute__((ext_vector_type(2))) _Float16;
using h8f = __attribute__((ext_vector_type(8))) _Float16;
using f4  = __attribute__((ext_vector_type(4))) float;

// ---------------------------------------------------------------------------
// prep: (a) Wfrag1/Wfrag2 fragment packing (as before)
// (b) zero agg2|g (410,000 floats contiguous)
// (c) pre1[n,i] = bias1[i] + sum_d x[n,d]*root1[d,i]   (written into agg1 slot;
//     edge1 atomics accumulate on top; consumers apply relu on read)
// ---------------------------------------------------------------------------
__global__ __launch_bounds__(256) void prep_kernel(
    const float* __restrict__ nn1W, const float* __restrict__ nn1b,
    const float* __restrict__ nn2W, const float* __restrict__ nn2b,
    const float* __restrict__ root1, const float* __restrict__ bias1,
    const float* __restrict__ x,
    unsigned short* __restrict__ Wfrag1, unsigned short* __restrict__ Wfrag2,
    float* __restrict__ pre1, float* __restrict__ zbase)
{
  __shared__ float sroot1[D_IN * H1];   // 12.8 KB
  __shared__ float sxl[YNB * D_IN];
  const int t   = threadIdx.x;
  const int tid = blockIdx.x * 256 + t;

  // (a) fragment packing
  if (tid < 544 * 112) {
    const int c  = tid / 3584;
    const int r  = tid % 3584;
    const int to = r / 512;
    const int l  = (r % 512) >> 3;
    const int j  = r & 7;
    const int i  = (l >> 4) * 8 + j;
    const int o  = to * 16 + (l & 15);
    float v = 0.f;
    if (o < H1) v = (c < 16) ? nn1W[c * (D_IN * H1) + i * H1 + o] : nn1b[i * H1 + o];
    _Float16 hv = (_Float16)v;
    Wfrag1[tid] = __builtin_bit_cast(unsigned short, hv);
  } else if (tid < 544 * 112 + 17 * 4096) {
    const int t2 = tid - 544 * 112;
    const int c  = t2 >> 12;
    const int q  = (t2 >> 10) & 3;
    const int to = (t2 >> 9) & 1;
    const int l  = (t2 >> 3) & 63;
    const int j  = t2 & 7;
    const int i  = q * 32 + (l >> 4) * 8 + j;
    const int o  = to * 16 + (l & 15);
    float v = 0.f;
    if (i < H1 && o < H2)
      v = (c < 16) ? nn2W[c * (H1 * H2) + i * H2 + o] : nn2b[i * H2 + o];
    _Float16 hv = (_Float16)v;
    Wfrag2[t2] = __builtin_bit_cast(unsigned short, hv);
  }

  // (b) zero agg2|g : 410,000 floats = 102,500 float4
  {
    float4* zp = (float4*)zbase;
    for (int i = tid; i < 102500; i += 512 * 256)
      zp[i] = make_float4(0.f, 0.f, 0.f, 0.f);
  }

  // (c) pre1 = x @ root1 + bias1, 12-node tiles, grid-stride
  for (int idx = t; idx < 800; idx += 256)
    *(float4*)&sroot1[idx * 4] = *(const float4*)&root1[idx * 4];

  for (int tile = blockIdx.x; tile < 1667; tile += 512) {
    const int n0 = tile * YNB;
    __syncthreads();   // previous iteration's sxl readers done
    if (t < 96) {
      const int fo = t * 4;
      const int nn = fo >> 5;
      float4 v = make_float4(0.f, 0.f, 0.f, 0.f);
      if (n0 + nn < N_NODES) v = *(const float4*)&x[(size_t)n0 * D_IN + fo];
      *(float4*)&sxl[fo] = v;
    }
    __syncthreads();
    for (int idx = t; idx < YNB * H1; idx += 256) {
      const int nn = idx / H1, i = idx - nn * H1;
      const int n = n0 + nn;
      if (n < N_NODES) {
        float v = bias1[i];
        #pragma unroll 8
        for (int d = 0; d < D_IN; ++d)
          v = fmaf(sxl[nn * D_IN + d], sroot1[d * H1 + i], v);
        pre1[(size_t)n0 * H1 + idx] = v;
      }
    }
  }
}

// ---------------------------------------------------------------------------
// Layer 1 edge messages via fp16 MFMA (unchanged, verified):
//   msg[e,o] = sum_j P[e,j]*W1'[j,o],  P[e,c*32+i] = ea[e,c]*x[src[e],i]
// atomics accumulate into pre1 (x@root1+bias1 already there)
// ---------------------------------------------------------------------------
__global__ __launch_bounds__(256, 3) void edge1_kernel(
    const float* __restrict__ x, const float* __restrict__ ea,
    const int* __restrict__ eidx, const unsigned short* __restrict__ Wfrag,
    float* __restrict__ agg1)
{
  __shared__ uint4 Plds[4 * 64];
  __shared__ uint4 Blds[2][7 * 64];
  __shared__ int   sdst[EB1];

  const int t    = threadIdx.x;
  const int lane = t & 63;
  const int w    = t >> 6;
  const int e0   = blockIdx.x * EB1;

  const int e_loc = t >> 2;
  const int jg    = t & 3;
  const int src   = eidx[e0 + e_loc];

  h2f xh[4];
  {
    const float4* xp = (const float4*)&x[(size_t)src * D_IN + jg * 8];
    float4 v0 = xp[0], v1 = xp[1];
    float xf[8] = {v0.x, v0.y, v0.z, v0.w, v1.x, v1.y, v1.z, v1.w};
    #pragma unroll
    for (int j = 0; j < 4; ++j) {
      h2f p; p[0] = (_Float16)xf[2*j]; p[1] = (_Float16)xf[2*j+1]; xh[j] = p;
    }
  }
  _Float16 eh[17];
  {
    const float4* ep = (const float4*)&ea[(size_t)(e0 + e_loc) * D_E];
    float4 v0 = ep[0], v1 = ep[1], v2 = ep[2], v3 = ep[3];
    float ef[16] = {v0.x,v0.y,v0.z,v0.w, v1.x,v1.y,v1.z,v1.w,
                    v2.x,v2.y,v2.z,v2.w, v3.x,v3.y,v3.z,v3.w};
    #pragma unroll
    for (int k = 0; k < 16; ++k) eh[k] = (_Float16)ef[k];
    eh[16] = (_Float16)1.0f;
  }
  if (t < EB1) sdst[t] = eidx[N_EDGES + e0 + t];

  const uint4* __restrict__ Bf = (const uint4*)Wfrag;
  {
    uint4 s0 = Bf[t];
    uint4 s1;
    if (t < 192) s1 = Bf[256 + t];
    Blds[0][t] = s0;
    if (t < 192) Blds[0][256 + t] = s1;
  }
  __syncthreads();

  f4 acc[7];
  #pragma unroll
  for (int to = 0; to < 7; ++to) acc[to] = f4{0.f, 0.f, 0.f, 0.f};

  const int pslot = w * 64 + (e_loc & 15) + 16 * jg;

  #pragma unroll
  for (int c = 0; c < 17; ++c) {
    uint4 s0, s1;
    if (c < 16) {
      const uint4* bn = Bf + (c + 1) * 448;
      s0 = bn[t];
      if (t < 192) s1 = bn[256 + t];
    }
    h2f es; es[0] = eh[c]; es[1] = eh[c];
    unsigned int pk[4];
    #pragma unroll
    for (int j = 0; j < 4; ++j) {
      h2f pr = xh[j] * es;
      pk[j] = __builtin_bit_cast(unsigned int, pr);
    }
    Plds[pslot] = make_uint4(pk[0], pk[1], pk[2], pk[3]);

    uint4 a = Plds[w * 64 + lane];
    h8f A = __builtin_bit_cast(h8f, a);

    const uint4* bb = &Blds[c & 1][0];
    #pragma unroll
    for (int to = 0; to < 7; ++to) {
      h8f B = __builtin_bit_cast(h8f, bb[to * 64 + lane]);
      acc[to] = __builtin_amdgcn_mfma_f32_16x16x32_f16(A, B, acc[to], 0, 0, 0);
    }
    if (c < 16) {
      Blds[(c + 1) & 1][t] = s0;
      if (t < 192) Blds[(c + 1) & 1][256 + t] = s1;
    }
    __syncthreads();
  }

  const int col = lane & 15, rowg = lane >> 4;
  #pragma unroll
  for (int r = 0; r < 4; ++r) {
    const int el = w * 16 + rowg * 4 + r;
    const int d = sdst[el];
    float* ap = agg1 + (size_t)d * H1;
    #pragma unroll
    for (int to = 0; to < 7; ++to) {
      const int o = to * 16 + col;
      if (o < H1) unsafeAtomicAdd(&ap[o], acc[to][r]);
    }
  }
}

// ---------------------------------------------------------------------------
// Layer 2 edge messages via fp16 MFMA; h1 = relu(pre1) applied on load.
// ---------------------------------------------------------------------------
__global__ __launch_bounds__(256, 3) void edge2m_kernel(
    const float* __restrict__ pre1, const float* __restrict__ ea,
    const int* __restrict__ eidx, const unsigned short* __restrict__ Wfrag2,
    float* __restrict__ agg2)
{
  __shared__ uint4 Plds[4][4][64];
  __shared__ uint4 Blds[2][512];
  __shared__ int   sdst[EB1];

  const int t    = threadIdx.x;
  const int lane = t & 63;
  const int w    = t >> 6;
  const int e0   = blockIdx.x * EB1;

  const int e_loc = t >> 2;
  const int jg    = t & 3;
  const int m     = e_loc & 15;
  const int src   = eidx[e0 + e_loc];

  h2f xh[16];
  {
    float xf[32];
    const float* hp = &pre1[(size_t)src * H1 + jg * 32];
    if (jg < 3) {
      #pragma unroll
      for (int q4 = 0; q4 < 8; ++q4) {
        float4 v = *(const float4*)&hp[q4 * 4];
        xf[q4*4+0] = fmaxf(v.x, 0.f); xf[q4*4+1] = fmaxf(v.y, 0.f);
        xf[q4*4+2] = fmaxf(v.z, 0.f); xf[q4*4+3] = fmaxf(v.w, 0.f);
      }
    } else {
      float4 v = *(const float4*)hp;   // features 96..99
      xf[0] = fmaxf(v.x, 0.f); xf[1] = fmaxf(v.y, 0.f);
      xf[2] = fmaxf(v.z, 0.f); xf[3] = fmaxf(v.w, 0.f);
      #pragma unroll
      for (int ii = 4; ii < 32; ++ii) xf[ii] = 0.f;
    }
    #pragma unroll
    for (int j2 = 0; j2 < 16; ++j2) {
      h2f p; p[0] = (_Float16)xf[2*j2]; p[1] = (_Float16)xf[2*j2+1]; xh[j2] = p;
    }
  }
  _Float16 eh[17];
  {
    const float4* ep = (const float4*)&ea[(size_t)(e0 + e_loc) * D_E];
    float4 v0 = ep[0], v1 = ep[1], v2 = ep[2], v3 = ep[3];
    float ef[16] = {v0.x,v0.y,v0.z,v0.w, v1.x,v1.y,v1.z,v1.w,
                    v2.x,v2.y,v2.z,v2.w, v3.x,v3.y,v3.z,v3.w};
    #pragma unroll
    for (int k = 0; k < 16; ++k) eh[k] = (_Float16)ef[k];
    eh[16] = (_Float16)1.0f;
  }
  if (t < EB1) sdst[t] = eidx[N_EDGES + e0 + t];

  const uint4* __restrict__ Bf = (const uint4*)Wfrag2;
  {
    uint4 s0 = Bf[t];
    uint4 s1 = Bf[256 + t];
    Blds[0][t] = s0;
    Blds[0][256 + t] = s1;
  }
  {
    h2f es; es[0] = eh[0]; es[1] = eh[0];
    unsigned int pk[16];
    #pragma unroll
    for (int j2 = 0; j2 < 16; ++j2) {
      h2f pr = xh[j2] * es;
      pk[j2] = __builtin_bit_cast(unsigned int, pr);
    }
    #pragma unroll
    for (int oc = 0; oc < 4; ++oc)
      Plds[w][jg][16 * oc + m] = make_uint4(pk[4*oc], pk[4*oc+1], pk[4*oc+2], pk[4*oc+3]);
  }
  __syncthreads();

  f4 acc0 = f4{0.f, 0.f, 0.f, 0.f};
  f4 acc1 = f4{0.f, 0.f, 0.f, 0.f};

  #pragma unroll
  for (int c = 0; c < 17; ++c) {
    const int buf = c & 1;
    uint4 s0, s1;
    if (c < 16) {
      const uint4* bn = Bf + (c + 1) * 512;
      s0 = bn[t];
      s1 = bn[256 + t];
    }
    #pragma unroll
    for (int q = 0; q < 4; ++q) {
      uint4 a  = Plds[w][q][lane];
      uint4 b0 = Blds[buf][q * 128 + lane];
      uint4 b1 = Blds[buf][q * 128 + 64 + lane];
      h8f A  = __builtin_bit_cast(h8f, a);
      h8f B0 = __builtin_bit_cast(h8f, b0);
      h8f B1 = __builtin_bit_cast(h8f, b1);
      acc0 = __builtin_amdgcn_mfma_f32_16x16x32_f16(A, B0, acc0, 0, 0, 0);
      acc1 = __builtin_amdgcn_mfma_f32_16x16x32_f16(A, B1, acc1, 0, 0, 0);
    }
    if (c < 16) {
      h2f es; es[0] = eh[c + 1]; es[1] = eh[c + 1];
      unsigned int pk[16];
      #pragma unroll
      for (int j2 = 0; j2 < 16; ++j2) {
        h2f pr = xh[j2] * es;
        pk[j2] = __builtin_bit_cast(unsigned int, pr);
      }
      #pragma unroll
      for (int oc = 0; oc < 4; ++oc)
        Plds[w][jg][16 * oc + m] = make_uint4(pk[4*oc], pk[4*oc+1], pk[4*oc+2], pk[4*oc+3]);
      Blds[buf ^ 1][t] = s0;
      Blds[buf ^ 1][256 + t] = s1;
      __syncthreads();
    }
  }

  const int col = lane & 15, rowg = lane >> 4;
  #pragma unroll
  for (int r = 0; r < 4; ++r) {
    const int el = w * 16 + rowg * 4 + r;
    const int d  = sdst[el];
    float* ap = agg2 + (size_t)d * H2;
    unsafeAtomicAdd(&ap[col], acc0[r]);
    if (col < 4) unsafeAtomicAdd(&ap[16 + col], acc1[r]);
  }
}

// ---------------------------------------------------------------------------
// Fused node update 2 + sum-pool; h1 = relu(pre1) applied on load.
// ---------------------------------------------------------------------------
__global__ __launch_bounds__(256) void node2_pool_kernel(
    const float* __restrict__ pre1, const float* __restrict__ agg2,
    const float* __restrict__ root2, const float* __restrict__ bias2,
    const int* __restrict__ batch, float* __restrict__ g)
{
  __shared__ float sroot[H1 * H2];
  __shared__ float sv[ET3][H2];
  __shared__ int   sg[ET3];
  const int t  = threadIdx.x;
  const int n0 = blockIdx.x * ET3;

  for (int idx = t; idx < (H1 * H2) / 4; idx += 256)
    *(float4*)&sroot[idx * 4] = *(const float4*)&root2[idx * 4];
  if (t < ET3) {
    const int n = n0 + t;
    sg[t] = (n < N_NODES) ? batch[n] : -1;
  }
  __syncthreads();

  const int nl = t / H2, o = t % H2;
  const int n = n0 + nl;
  if (nl < ET3) {
    float v = 0.f;
    if (n < N_NODES) {
      v = agg2[(size_t)n * H2 + o] + bias2[o];
      const float* hr = &pre1[(size_t)n * H1];
      #pragma unroll 5
      for (int i = 0; i < H1; i += 4) {
        const float4 hv = *(const float4*)&hr[i];
        v = fmaf(fmaxf(hv.x, 0.f), sroot[(i    ) * H2 + o], v);
        v = fmaf(fmaxf(hv.y, 0.f), sroot[(i + 1) * H2 + o], v);
        v = fmaf(fmaxf(hv.z, 0.f), sroot[(i + 2) * H2 + o], v);
        v = fmaf(fmaxf(hv.w, 0.f), sroot[(i + 3) * H2 + o], v);
      }
      v = fmaxf(v, 0.f);
    }
    sv[nl][o] = v;
  }
  __syncthreads();

  if (t < H2) {
    float run = 0.f;
    int cur = sg[0];
    #pragma unroll
    for (int r = 0; r < ET3; ++r) {
      const int gid = sg[r];
      if (gid != cur) {
        if (cur >= 0) unsafeAtomicAdd(&g[cur * H2 + t], run);
        run = 0.f; cur = gid;
      }
      run += sv[r][t];
    }
    if (cur >= 0) unsafeAtomicAdd(&g[cur * H2 + t], run);
  }
}

// ---------------------------------------------------------------------------
// Final MLP
// ---------------------------------------------------------------------------
__global__ __launch_bounds__(64) void final_kernel(
    const float* __restrict__ g, const float* __restrict__ lin1W,
    const float* __restrict__ lin1b, const float* __restrict__ lin2W,
    const float* __restrict__ lin2b, float* __restrict__ out)
{
  const int gr = blockIdx.x;
  const int tt = threadIdx.x;
  float v = 0.f;
  if (tt < F1) {
    float s = lin1b[tt];
    #pragma unroll
    for (int o = 0; o < H2; ++o) s = fmaf(g[gr * H2 + o], lin1W[o * F1 + tt], s);
    v = fmaxf(s, 0.f) * lin2W[tt];
  }
  #pragma unroll
  for (int off = 32; off > 0; off >>= 1) v += __shfl_down(v, off, 64);
  if (tt == 0) out[gr] = v + lin2b[0];
}

extern "C" void kernel_launch(void* const* d_in, const int* in_sizes, int n_in,
                              void* d_out, int out_size, void* d_ws, size_t ws_size,
                              hipStream_t stream) {
  const float* x     = (const float*)d_in[0];
  const float* ea    = (const float*)d_in[1];
  const int*   eidx  = (const int*)d_in[2];
  const int*   batch = (const int*)d_in[3];
  const float* nn1W  = (const float*)d_in[4];
  const float* nn1b  = (const float*)d_in[5];
  const float* root1 = (const float*)d_in[6];
  const float* bias1 = (const float*)d_in[7];
  const float* nn2W  = (const float*)d_in[8];
  const float* nn2b  = (const float*)d_in[9];
  const float* root2 = (const float*)d_in[10];
  const float* bias2 = (const float*)d_in[11];
  const float* lin1W = (const float*)d_in[12];
  const float* lin1b = (const float*)d_in[13];
  const float* lin2W = (const float*)d_in[14];
  const float* lin2b = (const float*)d_in[15];
  float* out = (float*)d_out;

  float* ws   = (float*)d_ws;
  float* pre1 = ws;                          // 2,000,000 floats (old agg1 slot)
  float* agg2 = pre1 + N_NODES * H1;         //   400,000
  float* g    = agg2 + N_NODES * H2;         //    10,000
  float* h1   = g    + N_GRAPHS * H2;        // 2,000,000 (unused; layout kept)
  unsigned short* Wfrag1 = (unsigned short*)(h1 + (size_t)N_NODES * H1);  // 60,928 u16
  unsigned short* Wfrag2 = Wfrag1 + 61440;                                // 69,632 u16

  prep_kernel<<<512, 256, 0, stream>>>(nn1W, nn1b, nn2W, nn2b, root1, bias1, x,
                                       Wfrag1, Wfrag2, pre1, agg2);
  edge1_kernel<<<N_EDGES / EB1, 256, 0, stream>>>(x, ea, eidx, Wfrag1, pre1);
  edge2m_kernel<<<N_EDGES / EB1, 256, 0, stream>>>(pre1, ea, eidx, Wfrag2, agg2);
  node2_pool_kernel<<<(N_NODES + ET3 - 1) / ET3, 256, 0, stream>>>(
      pre1, agg2, root2, bias2, batch, g);
  final_kernel<<<N_GRAPHS, 64, 0, stream>>>(g, lin1W, lin1b, lin2W, lin2b, out);
}